// Round 1
// baseline (2436.862 us; speedup 1.0000x reference)
//
#include <hip/hip_runtime.h>

// Problem constants (B=4, C=256, H=W=56, heads=8)
#define NUM_B 4
#define NUM_G 8
#define HD    32
#define LSP   3136            // 56*56
#define BG    (NUM_B*NUM_G)

#define TPB 256
#define KT  64                // k-tile for Z pass (3136 % 64 == 0)
#define JT  64                // j-tile for out pass

// ---------------- Kernel 1: grouped 1x1 conv -> q,k,v ----------------
__global__ __launch_bounds__(TPB) void qkv_kernel(
    const float* __restrict__ x,
    const float* __restrict__ Wq, const float* __restrict__ bq,
    const float* __restrict__ Wk, const float* __restrict__ bk,
    const float* __restrict__ Wv, const float* __restrict__ bv,
    float* __restrict__ q, float* __restrict__ k, float* __restrict__ v)
{
    const int bg = blockIdx.y;          // 0..31  (b*8+g)
    const int g  = bg & (NUM_G - 1);
    const int t  = threadIdx.x;

    __shared__ float sW[3 * HD * HD];
    __shared__ float sB[3 * HD];
    for (int i = t; i < HD * HD; i += TPB) {
        sW[i]             = Wq[g * HD * HD + i];
        sW[HD * HD + i]   = Wk[g * HD * HD + i];
        sW[2 * HD * HD + i] = Wv[g * HD * HD + i];
    }
    if (t < HD) {
        sB[t]          = bq[g * HD + t];
        sB[HD + t]     = bk[g * HD + t];
        sB[2 * HD + t] = bv[g * HD + t];
    }
    __syncthreads();

    const int l = blockIdx.x * TPB + t;
    if (l >= LSP) return;

    const size_t base = (size_t)bg * HD * LSP + l;
    float xv[HD];
#pragma unroll
    for (int i = 0; i < HD; ++i) xv[i] = x[base + (size_t)i * LSP];

    for (int o = 0; o < HD; ++o) {
        float aq = sB[o], ak = sB[HD + o], av = sB[2 * HD + o];
#pragma unroll
        for (int i = 0; i < HD; ++i) {
            const float xi = xv[i];
            aq = fmaf(sW[o * HD + i],              xi, aq);
            ak = fmaf(sW[HD * HD + o * HD + i],    xi, ak);
            av = fmaf(sW[2 * HD * HD + o * HD + i], xi, av);
        }
        q[base + (size_t)o * LSP] = aq;
        k[base + (size_t)o * LSP] = ak;
        v[base + (size_t)o * LSP] = av;
    }
}

// ---------------- Kernel 2: Z[j] = sum_k exp(q_j . k_k); store 1/Z ----------------
__global__ __launch_bounds__(TPB) void z_kernel(
    const float* __restrict__ q, const float* __restrict__ kmat,
    float* __restrict__ rz)
{
    const int bg = blockIdx.y;
    const int j  = blockIdx.x * TPB + threadIdx.x;
    const float* qp = q    + (size_t)bg * HD * LSP;
    const float* kp = kmat + (size_t)bg * HD * LSP;

    float qv[HD];
    if (j < LSP) {
#pragma unroll
        for (int d = 0; d < HD; ++d) qv[d] = qp[(size_t)d * LSP + j];
    }

    __shared__ float sk[HD * KT];   // [d][kk]
    float z = 0.f;

    for (int k0 = 0; k0 < LSP; k0 += KT) {
        __syncthreads();
        for (int i = threadIdx.x; i < HD * KT; i += TPB) {
            const int d  = i / KT;
            const int kk = i - d * KT;
            sk[i] = kp[(size_t)d * LSP + k0 + kk];
        }
        __syncthreads();
        if (j < LSP) {
            for (int kk = 0; kk < KT; ++kk) {
                // split dot into 4 partials for ILP
                float e0 = 0.f, e1 = 0.f, e2 = 0.f, e3 = 0.f;
#pragma unroll
                for (int d = 0; d < HD; d += 4) {
                    e0 = fmaf(qv[d + 0], sk[(d + 0) * KT + kk], e0);
                    e1 = fmaf(qv[d + 1], sk[(d + 1) * KT + kk], e1);
                    e2 = fmaf(qv[d + 2], sk[(d + 2) * KT + kk], e2);
                    e3 = fmaf(qv[d + 3], sk[(d + 3) * KT + kk], e3);
                }
                z += __expf((e0 + e1) + (e2 + e3));
            }
        }
    }
    if (j < LSP) rz[(size_t)bg * LSP + j] = 1.0f / z;
}

// ---------------- Kernel 3: out[d,k] = sum_j exp(q_j.k_k) * v[d,j]/Z[j], + x ----------------
__global__ __launch_bounds__(TPB) void out_kernel(
    const float* __restrict__ q, const float* __restrict__ kmat,
    const float* __restrict__ v, const float* __restrict__ rz,
    const float* __restrict__ x, float* __restrict__ out)
{
    const int bg   = blockIdx.y;
    const int kIdx = blockIdx.x * TPB + threadIdx.x;
    const float* qp = q    + (size_t)bg * HD * LSP;
    const float* kp = kmat + (size_t)bg * HD * LSP;
    const float* vp = v    + (size_t)bg * HD * LSP;
    const float* rzp = rz  + (size_t)bg * LSP;

    float kv[HD];
    if (kIdx < LSP) {
#pragma unroll
        for (int d = 0; d < HD; ++d) kv[d] = kp[(size_t)d * LSP + kIdx];
    }

    __shared__ float sq[HD * JT];    // [d][jj]
    __shared__ float svz[HD * JT];   // v[d,j] * (1/Z[j])
    float acc[HD];
#pragma unroll
    for (int d = 0; d < HD; ++d) acc[d] = 0.f;

    for (int j0 = 0; j0 < LSP; j0 += JT) {
        __syncthreads();
        for (int i = threadIdx.x; i < HD * JT; i += TPB) {
            const int d  = i / JT;
            const int jj = i - d * JT;
            sq[i]  = qp[(size_t)d * LSP + j0 + jj];
            svz[i] = vp[(size_t)d * LSP + j0 + jj] * rzp[j0 + jj];
        }
        __syncthreads();
        if (kIdx < LSP) {
            for (int jj = 0; jj < JT; ++jj) {
                float e0 = 0.f, e1 = 0.f, e2 = 0.f, e3 = 0.f;
#pragma unroll
                for (int d = 0; d < HD; d += 4) {
                    e0 = fmaf(kv[d + 0], sq[(d + 0) * JT + jj], e0);
                    e1 = fmaf(kv[d + 1], sq[(d + 1) * JT + jj], e1);
                    e2 = fmaf(kv[d + 2], sq[(d + 2) * JT + jj], e2);
                    e3 = fmaf(kv[d + 3], sq[(d + 3) * JT + jj], e3);
                }
                const float w = __expf((e0 + e1) + (e2 + e3));
#pragma unroll
                for (int d = 0; d < HD; ++d)
                    acc[d] = fmaf(w, svz[d * JT + jj], acc[d]);
            }
        }
    }

    if (kIdx < LSP) {
        const size_t base = (size_t)bg * HD * LSP + kIdx;
#pragma unroll
        for (int d = 0; d < HD; ++d)
            out[base + (size_t)d * LSP] = acc[d] + x[base + (size_t)d * LSP];
    }
}

extern "C" void kernel_launch(void* const* d_in, const int* in_sizes, int n_in,
                              void* d_out, int out_size, void* d_ws, size_t ws_size,
                              hipStream_t stream) {
    const float* x  = (const float*)d_in[0];
    const float* Wq = (const float*)d_in[1];
    const float* bq = (const float*)d_in[2];
    const float* Wk = (const float*)d_in[3];
    const float* bk = (const float*)d_in[4];
    const float* Wv = (const float*)d_in[5];
    const float* bv = (const float*)d_in[6];
    float* out = (float*)d_out;

    // workspace layout: q | k | v | rz   (~38.9 MB total, fp32)
    const size_t QSZ = (size_t)BG * HD * LSP;     // 3,211,264 floats
    float* q  = (float*)d_ws;
    float* k  = q + QSZ;
    float* v  = k + QSZ;
    float* rz = v + QSZ;                          // BG*LSP floats

    const int nxblk = (LSP + TPB - 1) / TPB;      // 13
    dim3 grid(nxblk, BG);

    qkv_kernel<<<grid, TPB, 0, stream>>>(x, Wq, bq, Wk, bk, Wv, bv, q, k, v);
    z_kernel<<<grid, TPB, 0, stream>>>(q, k, rz);
    out_kernel<<<grid, TPB, 0, stream>>>(q, k, v, rz, x, out);
}

// Round 2
// 422.597 us; speedup vs baseline: 5.7664x; 5.7664x over previous
//
#include <hip/hip_runtime.h>

// Problem constants (B=4, C=256, H=W=56, heads=8)
#define NUM_B 4
#define NUM_G 8
#define HD    32
#define LSP   3136            // 56*56  (= 49*64, all tiles divide exactly)
#define BG    (NUM_B*NUM_G)

#define TPB 256

typedef short bf16x8 __attribute__((ext_vector_type(8)));
typedef short short4v __attribute__((ext_vector_type(4)));
typedef float f32x4  __attribute__((ext_vector_type(4)));

// round-to-nearest-even float -> bf16 (values are finite; no NaN handling)
__device__ __forceinline__ short f2bf(float f) {
    unsigned u = __float_as_uint(f);
    u += 0x7FFFu + ((u >> 16) & 1u);
    return (short)(u >> 16);
}

// ---------------- Kernel 1: grouped 1x1 conv -> q_t, k_t (bf16 [L][32]), v (bf16 [32][L]) ----------------
__global__ __launch_bounds__(TPB) void qkv_kernel(
    const float* __restrict__ x,
    const float* __restrict__ Wq, const float* __restrict__ bq,
    const float* __restrict__ Wk, const float* __restrict__ bk,
    const float* __restrict__ Wv, const float* __restrict__ bv,
    short* __restrict__ qt, short* __restrict__ kt, short* __restrict__ v)
{
    const int bg = blockIdx.y;          // 0..31  (b*8+g)
    const int g  = bg & (NUM_G - 1);
    const int t  = threadIdx.x;

    __shared__ float sW[3 * HD * HD];
    __shared__ float sB[3 * HD];
    for (int i = t; i < HD * HD; i += TPB) {
        sW[i]               = Wq[g * HD * HD + i];
        sW[HD * HD + i]     = Wk[g * HD * HD + i];
        sW[2 * HD * HD + i] = Wv[g * HD * HD + i];
    }
    if (t < HD) {
        sB[t]          = bq[g * HD + t];
        sB[HD + t]     = bk[g * HD + t];
        sB[2 * HD + t] = bv[g * HD + t];
    }
    __syncthreads();

    const int l = blockIdx.x * TPB + t;
    if (l >= LSP) return;

    const size_t xbase = (size_t)bg * HD * LSP + l;
    float xv[HD];
#pragma unroll
    for (int i = 0; i < HD; ++i) xv[i] = x[xbase + (size_t)i * LSP];

    short qrow[HD], krow[HD];
    short* vb = v + (size_t)bg * HD * LSP;

#pragma unroll
    for (int o = 0; o < HD; ++o) {
        float aq = sB[o], ak = sB[HD + o], av = sB[2 * HD + o];
#pragma unroll
        for (int i = 0; i < HD; ++i) {
            const float xi = xv[i];
            aq = fmaf(sW[o * HD + i],               xi, aq);
            ak = fmaf(sW[HD * HD + o * HD + i],     xi, ak);
            av = fmaf(sW[2 * HD * HD + o * HD + i], xi, av);
        }
        qrow[o] = f2bf(aq);
        krow[o] = f2bf(ak);
        vb[(size_t)o * LSP + l] = f2bf(av);     // coalesced across lanes
    }

    // q_t / k_t rows: 32 bf16 = 64B contiguous per thread
    short* qrp = qt + ((size_t)bg * LSP + l) * HD;
    short* krp = kt + ((size_t)bg * LSP + l) * HD;
#pragma unroll
    for (int c = 0; c < 4; ++c) {
        *(bf16x8*)(qrp + 8 * c) = *(bf16x8*)&qrow[8 * c];
        *(bf16x8*)(krp + 8 * c) = *(bf16x8*)&krow[8 * c];
    }
}

// ---------------- Kernel 2: rz[j] = 1 / sum_k exp(q_j . k_k)  (MFMA) ----------------
// block = (bg, 64-row j-tile); 4 waves split the k range.
__global__ __launch_bounds__(TPB) void z_mfma(
    const short* __restrict__ qt, const short* __restrict__ kt,
    float* __restrict__ rz)
{
    const int bg = blockIdx.y;
    const int j0 = blockIdx.x * 64;
    const int lane = threadIdx.x & 63;
    const int w    = threadIdx.x >> 6;
    const int m    = lane & 15;
    const int g    = lane >> 4;

    const short* qtb = qt + (size_t)bg * LSP * HD;
    const short* ktb = kt + (size_t)bg * LSP * HD;

    // A fragments: Q rows j0..j0+63 (4 sub-tiles of 16)
    bf16x8 aq[4];
#pragma unroll
    for (int jt = 0; jt < 4; ++jt)
        aq[jt] = *(const bf16x8*)(qtb + (size_t)(j0 + 16 * jt + m) * HD + 8 * g);

    float zacc[16];
#pragma unroll
    for (int i = 0; i < 16; ++i) zacc[i] = 0.f;

    const f32x4 zero = {0.f, 0.f, 0.f, 0.f};
    for (int k0 = 16 * w; k0 < LSP; k0 += 64) {
        bf16x8 bk = *(const bf16x8*)(ktb + (size_t)(k0 + m) * HD + 8 * g);
#pragma unroll
        for (int jt = 0; jt < 4; ++jt) {
            f32x4 c = __builtin_amdgcn_mfma_f32_16x16x32_bf16(aq[jt], bk, zero, 0, 0, 0);
#pragma unroll
            for (int r = 0; r < 4; ++r)
                zacc[4 * jt + r] += __expf(c[r]);
        }
    }

    // reduce over the 16 cols held by lanes m=0..15 (butterfly over lane bits 0-3)
#pragma unroll
    for (int i = 0; i < 16; ++i) {
#pragma unroll
        for (int off = 1; off < 16; off <<= 1)
            zacc[i] += __shfl_xor(zacc[i], off);
    }

    __shared__ float zlds[64];
    if (threadIdx.x < 64) zlds[threadIdx.x] = 0.f;
    __syncthreads();
    if (m == 0) {
#pragma unroll
        for (int jt = 0; jt < 4; ++jt)
#pragma unroll
            for (int r = 0; r < 4; ++r)
                atomicAdd(&zlds[16 * jt + 4 * g + r], zacc[4 * jt + r]);
    }
    __syncthreads();
    if (threadIdx.x < 64)
        rz[(size_t)bg * LSP + j0 + threadIdx.x] = 1.0f / zlds[threadIdx.x];
}

// ---------------- Kernel 3: out[d,k] = sum_j exp(q_j.k_k)*rz[j]*v[d,j] + x  (MFMA) ----------------
// block = (bg, 64-col k-tile); wave w owns cols k0+16w..+15.
// P goes C-layout -> B-operand layout through a wave-private padded LDS region (no barriers).
#define PSTR 72   // padded col stride (shorts): 16B-aligned, ~2-way banks
__global__ __launch_bounds__(TPB) void out_mfma(
    const short* __restrict__ qt, const short* __restrict__ kt,
    const short* __restrict__ v, const float* __restrict__ rz,
    const float* __restrict__ x, float* __restrict__ out)
{
    const int bg = blockIdx.y;
    const int k0 = blockIdx.x * 64;
    const int lane = threadIdx.x & 63;
    const int w    = threadIdx.x >> 6;
    const int m    = lane & 15;
    const int g    = lane >> 4;

    const short* qtb = qt + (size_t)bg * LSP * HD;
    const short* ktb = kt + (size_t)bg * LSP * HD;
    const short* vb  = v  + (size_t)bg * HD * LSP;
    const float* rzb = rz + (size_t)bg * LSP;

    __shared__ short plds[4][16 * PSTR];
    short* pw = plds[w];

    // B fragment of K for this wave's 16 cols (constant over j loop)
    const bf16x8 bk = *(const bf16x8*)(ktb + (size_t)(k0 + 16 * w + m) * HD + 8 * g);

    const f32x4 zero = {0.f, 0.f, 0.f, 0.f};
    f32x4 o0 = zero, o1 = zero;

    for (int j0 = 0; j0 < LSP; j0 += 64) {
        // ---- E tile (64 j-rows x 16 k-cols), P = exp(E)*rz -> bf16 -> LDS (col-major) ----
#pragma unroll
        for (int jt = 0; jt < 4; ++jt) {
            bf16x8 aq = *(const bf16x8*)(qtb + (size_t)(j0 + 16 * jt + m) * HD + 8 * g);
            f32x4 c = __builtin_amdgcn_mfma_f32_16x16x32_bf16(aq, bk, zero, 0, 0, 0);
            f32x4 rz4 = *(const f32x4*)(rzb + j0 + 16 * jt + 4 * g);
            short4v pk;
#pragma unroll
            for (int r = 0; r < 4; ++r)
                pk[r] = f2bf(__expf(c[r]) * rz4[r]);
            // C-layout value (row=16jt+4g+r, col=m) -> plds[col][row]
            *(short4v*)(pw + m * PSTR + 16 * jt + 4 * g) = pk;
        }
        // wave-private region: no __syncthreads needed (compiler inserts lgkmcnt)

        // ---- B fragments of P (rows j0..j0+63 in two K=32 chunks) ----
        bf16x8 bp0 = *(const bf16x8*)(pw + m * PSTR + 0  + 8 * g);
        bf16x8 bp1 = *(const bf16x8*)(pw + m * PSTR + 32 + 8 * g);

        // ---- out += V' x P ----
        {
            bf16x8 av = *(const bf16x8*)(vb + (size_t)(m) * LSP + j0 + 8 * g);
            o0 = __builtin_amdgcn_mfma_f32_16x16x32_bf16(av, bp0, o0, 0, 0, 0);
            av = *(const bf16x8*)(vb + (size_t)(m) * LSP + j0 + 32 + 8 * g);
            o0 = __builtin_amdgcn_mfma_f32_16x16x32_bf16(av, bp1, o0, 0, 0, 0);
        }
        {
            bf16x8 av = *(const bf16x8*)(vb + (size_t)(16 + m) * LSP + j0 + 8 * g);
            o1 = __builtin_amdgcn_mfma_f32_16x16x32_bf16(av, bp0, o1, 0, 0, 0);
            av = *(const bf16x8*)(vb + (size_t)(16 + m) * LSP + j0 + 32 + 8 * g);
            o1 = __builtin_amdgcn_mfma_f32_16x16x32_bf16(av, bp1, o1, 0, 0, 0);
        }
    }

    // epilogue: C layout row=(g*4+r) within 16-subtile, col=m
    const int kcol = k0 + 16 * w + m;
#pragma unroll
    for (int r = 0; r < 4; ++r) {
        int d = 4 * g + r;
        size_t idx = (size_t)bg * HD * LSP + (size_t)d * LSP + kcol;
        out[idx] = o0[r] + x[idx];
        d = 16 + 4 * g + r;
        idx = (size_t)bg * HD * LSP + (size_t)d * LSP + kcol;
        out[idx] = o1[r] + x[idx];
    }
}

extern "C" void kernel_launch(void* const* d_in, const int* in_sizes, int n_in,
                              void* d_out, int out_size, void* d_ws, size_t ws_size,
                              hipStream_t stream) {
    const float* x  = (const float*)d_in[0];
    const float* Wq = (const float*)d_in[1];
    const float* bq = (const float*)d_in[2];
    const float* Wk = (const float*)d_in[3];
    const float* bk = (const float*)d_in[4];
    const float* Wv = (const float*)d_in[5];
    const float* bv = (const float*)d_in[6];
    float* out = (float*)d_out;

    // workspace: qt | kt | v (bf16) | rz (fp32)   ~19.7 MB
    const size_t QSZ = (size_t)BG * HD * LSP;     // 3,211,264 elements
    short* qt = (short*)d_ws;
    short* kt = qt + QSZ;
    short* v  = kt + QSZ;
    float* rz = (float*)(v + QSZ);                // BG*LSP floats

    const int nxblk = (LSP + TPB - 1) / TPB;      // 13
    qkv_kernel<<<dim3(nxblk, BG), TPB, 0, stream>>>(x, Wq, bq, Wk, bk, Wv, bv, qt, kt, v);

    dim3 grid(LSP / 64, BG);                      // 49 x 32
    z_mfma  <<<grid, TPB, 0, stream>>>(qt, kt, rz);
    out_mfma<<<grid, TPB, 0, stream>>>(qt, kt, v, rz, x, out);
}

// Round 3
// 267.931 us; speedup vs baseline: 9.0951x; 1.5773x over previous
//
#include <hip/hip_runtime.h>

// Problem constants (B=4, C=256, H=W=56, heads=8)
#define NUM_G 8
#define HD    32
#define LSP   3136            // 56*56 = 49*64
#define BG    32
#define TPB   256
#define LOG2E 1.4426950408889634f

typedef short bf16x8 __attribute__((ext_vector_type(8)));
typedef float f32x4  __attribute__((ext_vector_type(4)));
typedef unsigned uint2v __attribute__((ext_vector_type(2)));
typedef unsigned uint4v __attribute__((ext_vector_type(4)));

union B8 { bf16x8 h; uint4v u; };

#if __has_builtin(__builtin_amdgcn_exp2f)
#define EXP2F __builtin_amdgcn_exp2f
#else
#define EXP2F exp2f
#endif

// pack two f32 -> two bf16 (RNE), low = a, high = b
__device__ __forceinline__ unsigned pk_bf16(float a, float b) {
#if __has_builtin(__builtin_amdgcn_cvt_pk_bf16_f32)
    typedef __bf16 bf16x2_t __attribute__((ext_vector_type(2)));
    bf16x2_t r = __builtin_amdgcn_cvt_pk_bf16_f32(a, b);
    unsigned u; __builtin_memcpy(&u, &r, 4); return u;
#else
    unsigned ua = __float_as_uint(a); ua += 0x7FFFu + ((ua >> 16) & 1u);
    unsigned ub = __float_as_uint(b); ub += 0x7FFFu + ((ub >> 16) & 1u);
    return (ua >> 16) | (ub & 0xFFFF0000u);
#endif
}

__device__ __forceinline__ short f2bf(float f) {
    unsigned u = __float_as_uint(f);
    u += 0x7FFFu + ((u >> 16) & 1u);
    return (short)(u >> 16);
}

__device__ __forceinline__ float bf2f(short s) {
    return __uint_as_float(((unsigned)(unsigned short)s) << 16);
}

// ---------------- Kernel 1: grouped 1x1 conv via MFMA ----------------
// qt[l][o] = (Wq x + bq)*log2e  (bf16, row-contig 64B)
// kt[l][o] =  Wk x + bk
// v [d][l] =  Wv x + bv
// x fragment: lane(m,g) holds x[i=8g..8g+7][l0+m] — serves as A (x^T) for q/k
// and as B (x) for v simultaneously.
__global__ __launch_bounds__(TPB, 4) void qkv_mfma(
    const float* __restrict__ x,
    const float* __restrict__ Wq, const float* __restrict__ bq,
    const float* __restrict__ Wk, const float* __restrict__ bk,
    const float* __restrict__ Wv, const float* __restrict__ bv,
    short* __restrict__ qt, short* __restrict__ kt, short* __restrict__ v)
{
    const int bg = blockIdx.y, gh = bg & (NUM_G - 1);
    const int lane = threadIdx.x & 63, w = threadIdx.x >> 6;
    const int m = lane & 15, g = lane >> 4;

    const float* xb = x + (size_t)bg * HD * LSP;
    short* qtb = qt + (size_t)bg * LSP * HD;
    short* ktb = kt + (size_t)bg * LSP * HD;
    short* vb  = v  + (size_t)bg * HD * LSP;

    // weight fragments (bf16): wq/wk as B-operand (cols o=16h+m), wv as A-operand (rows d=16h+m)
    B8 wqf[2], wkf[2], wvf[2];
    float bqv[2], bkv[2], bvv[2][4];
#pragma unroll
    for (int h = 0; h < 2; ++h) {
        const int o = 16 * h + m;
        const float* wqp = Wq + (size_t)(gh * HD + o) * HD + 8 * g;
        const float* wkp = Wk + (size_t)(gh * HD + o) * HD + 8 * g;
        const float* wvp = Wv + (size_t)(gh * HD + o) * HD + 8 * g;
#pragma unroll
        for (int p = 0; p < 4; ++p) {
            wqf[h].u[p] = pk_bf16(wqp[2*p] * LOG2E, wqp[2*p+1] * LOG2E); // fold log2e
            wkf[h].u[p] = pk_bf16(wkp[2*p],         wkp[2*p+1]);
            wvf[h].u[p] = pk_bf16(wvp[2*p],         wvp[2*p+1]);
        }
        bqv[h] = bq[gh * HD + o] * LOG2E;
        bkv[h] = bk[gh * HD + o];
#pragma unroll
        for (int r = 0; r < 4; ++r)
            bvv[h][r] = bv[gh * HD + 16 * h + 4 * g + r];
    }

    const int l0 = blockIdx.x * 256 + w * 64;
    const f32x4 zero = {0.f, 0.f, 0.f, 0.f};
#pragma unroll
    for (int c = 0; c < 4; ++c) {
        const int lc = l0 + 16 * c;
        int lrow = lc + m; if (lrow >= LSP) lrow = LSP - 1;
        B8 xf;
#pragma unroll
        for (int p = 0; p < 4; ++p) {
            const float a0 = xb[(size_t)(8*g + 2*p)     * LSP + lrow];
            const float a1 = xb[(size_t)(8*g + 2*p + 1) * LSP + lrow];
            xf.u[p] = pk_bf16(a0, a1);
        }
#pragma unroll
        for (int h = 0; h < 2; ++h) {
            f32x4 cq = __builtin_amdgcn_mfma_f32_16x16x32_bf16(xf.h, wqf[h].h, zero, 0, 0, 0);
            f32x4 ck = __builtin_amdgcn_mfma_f32_16x16x32_bf16(xf.h, wkf[h].h, zero, 0, 0, 0);
            f32x4 cv = __builtin_amdgcn_mfma_f32_16x16x32_bf16(wvf[h].h, xf.h, zero, 0, 0, 0);
            const int lcol = lc + m;
#pragma unroll
            for (int r = 0; r < 4; ++r) {
                const int lr = lc + 4 * g + r;
                if (lr < LSP) {
                    qtb[(size_t)lr * HD + 16 * h + m] = f2bf(cq[r] + bqv[h]);
                    ktb[(size_t)lr * HD + 16 * h + m] = f2bf(ck[r] + bkv[h]);
                }
                if (lcol < LSP)
                    vb[(size_t)(16 * h + 4 * g + r) * LSP + lcol] = f2bf(cv[r] + bvv[h][r]);
            }
        }
    }
}

// ---------------- Kernel 2: Z[j] = sum_k exp2(q'_j . k_k);  v[d,j] *= 1/Z[j] in-place ----------------
// block = (bg, 128-row j-group); 4 waves partition the 196 k-chunks of 16.
__global__ __launch_bounds__(TPB, 4) void z_mfma(
    const short* __restrict__ qt, const short* __restrict__ kt,
    short* __restrict__ v)
{
    const int bg = blockIdx.y;
    const int jb = blockIdx.x * 128;
    const int t = threadIdx.x;
    const int lane = t & 63, w = t >> 6, m = lane & 15, g = lane >> 4;

    const short* qtb = qt + (size_t)bg * LSP * HD;
    const short* ktb = kt + (size_t)bg * LSP * HD;
    short* vb = v + (size_t)bg * HD * LSP;

    bf16x8 aq[8];
#pragma unroll
    for (int jt = 0; jt < 8; ++jt) {
        int row = jb + 16 * jt + m; if (row >= LSP) row = LSP - 1;
        aq[jt] = *(const bf16x8*)(qtb + (size_t)row * HD + 8 * g);
    }

    f32x4 zacc[8];
#pragma unroll
    for (int jt = 0; jt < 8; ++jt) zacc[jt] = (f32x4){0.f, 0.f, 0.f, 0.f};

    const f32x4 zero = {0.f, 0.f, 0.f, 0.f};
    // wave w handles k-rows 64*it + 16*w + m
    bf16x8 bkf = *(const bf16x8*)(ktb + (size_t)(16 * w + m) * HD + 8 * g);
    for (int it = 0; it < 49; ++it) {
        const bf16x8 bkc = bkf;
        const int nxt = (it + 1 < 49) ? ((it + 1) * 64 + 16 * w + m) : (16 * w + m);
        bkf = *(const bf16x8*)(ktb + (size_t)nxt * HD + 8 * g);
#pragma unroll
        for (int jt = 0; jt < 8; ++jt) {
            f32x4 c = __builtin_amdgcn_mfma_f32_16x16x32_bf16(aq[jt], bkc, zero, 0, 0, 0);
#pragma unroll
            for (int r = 0; r < 4; ++r) zacc[jt][r] += EXP2F(c[r]);
        }
    }

    __shared__ float zl[128];
    if (t < 128) zl[t] = 0.f;
    __syncthreads();
#pragma unroll
    for (int jt = 0; jt < 8; ++jt) {
#pragma unroll
        for (int r = 0; r < 4; ++r) {
            float s = zacc[jt][r];
            s += __shfl_xor(s, 1); s += __shfl_xor(s, 2);
            s += __shfl_xor(s, 4); s += __shfl_xor(s, 8);
            if (m == 0) atomicAdd(&zl[16 * jt + 4 * g + r], s);
        }
    }
    __syncthreads();

    // scale v rows jb..jb+127 by 1/Z
    const int jl = (t & 15) * 8;     // 0..120
    const int d0 = t >> 4;           // 0..15
    const int j = jb + jl;
    if (j < LSP) {                   // vectors never straddle LSP (64 | LSP-jb boundary)
        float rzv[8];
#pragma unroll
        for (int e = 0; e < 8; ++e) rzv[e] = 1.0f / zl[jl + e];
#pragma unroll
        for (int hh = 0; hh < 2; ++hh) {
            short* vp = vb + (size_t)(d0 + 16 * hh) * LSP + j;
            bf16x8 vv = *(bf16x8*)vp;
            B8 o;
#pragma unroll
            for (int p = 0; p < 4; ++p)
                o.u[p] = pk_bf16(bf2f(vv[2*p]) * rzv[2*p], bf2f(vv[2*p+1]) * rzv[2*p+1]);
            *(bf16x8*)vp = o.h;
        }
    }
}

// ---------------- Kernel 3: out[d,k] = sum_j exp2(q'_j.k_k) * v'[d,j] + x ----------------
// block = (bg, 128-col group); wave w owns cols {16w..} and {64+16w..} (2 subtiles, ILP x2).
// P transposed C->B layout through wave-private XOR-swizzled LDS (conflict-free, no barriers).
__global__ __launch_bounds__(TPB, 3) void out_mfma(
    const short* __restrict__ qt, const short* __restrict__ kt,
    const short* __restrict__ v,
    const float* __restrict__ x, float* __restrict__ out)
{
    const int bg = blockIdx.y;
    const int lane = threadIdx.x & 63, w = threadIdx.x >> 6;
    const int m = lane & 15, g = lane >> 4;

    const short* qtb = qt + (size_t)bg * LSP * HD;
    const short* ktb = kt + (size_t)bg * LSP * HD;
    const short* vb  = v  + (size_t)bg * HD * LSP;

    const int kc0 = blockIdx.x * 128 + 16 * w + m;        // always real (<=3135)
    const int kc1 = kc0 + 64;
    const bool real1 = (kc1 < LSP);
    const int kc1c = real1 ? kc1 : (LSP - 1);

    const bf16x8 bk0 = *(const bf16x8*)(ktb + (size_t)kc0  * HD + 8 * g);
    const bf16x8 bk1 = *(const bf16x8*)(ktb + (size_t)kc1c * HD + 8 * g);

    // per-wave 2 regions of 16 cols x 32 dwords; XOR swizzle pat=(m&3)<<3 on dword row idx
    __shared__ unsigned plds[4][2][512];
    unsigned* p0 = &plds[w][0][0];
    unsigned* p1 = &plds[w][1][0];
    const int pat = (m & 3) << 3;
    const int colbase = m * 32;

    const f32x4 zero = {0.f, 0.f, 0.f, 0.f};
    f32x4 o00 = zero, o01 = zero, o10 = zero, o11 = zero;

    bf16x8 aq[4];
#pragma unroll
    for (int jt = 0; jt < 4; ++jt)
        aq[jt] = *(const bf16x8*)(qtb + (size_t)(16 * jt + m) * HD + 8 * g);

    for (int j0 = 0; j0 < LSP; j0 += 64) {
        // v' loads issued early (consumed at end of iter)
        const bf16x8 av0 = *(const bf16x8*)(vb + (size_t)m        * LSP + j0      + 8 * g);
        const bf16x8 av1 = *(const bf16x8*)(vb + (size_t)m        * LSP + j0 + 32 + 8 * g);
        const bf16x8 av2 = *(const bf16x8*)(vb + (size_t)(16 + m) * LSP + j0      + 8 * g);
        const bf16x8 av3 = *(const bf16x8*)(vb + (size_t)(16 + m) * LSP + j0 + 32 + 8 * g);

        const int jn = (j0 + 64 < LSP) ? (j0 + 64) : 0;   // prefetch target (wraps; unused last iter)
#pragma unroll
        for (int jt = 0; jt < 4; ++jt) {
            const f32x4 e0 = __builtin_amdgcn_mfma_f32_16x16x32_bf16(aq[jt], bk0, zero, 0, 0, 0);
            const f32x4 e1 = __builtin_amdgcn_mfma_f32_16x16x32_bf16(aq[jt], bk1, zero, 0, 0, 0);
            aq[jt] = *(const bf16x8*)(qtb + (size_t)(jn + 16 * jt + m) * HD + 8 * g); // prefetch
            uint2v w0, w1;
            w0[0] = pk_bf16(EXP2F(e0[0]), EXP2F(e0[1]));
            w0[1] = pk_bf16(EXP2F(e0[2]), EXP2F(e0[3]));
            w1[0] = pk_bf16(EXP2F(e1[0]), EXP2F(e1[1]));
            w1[1] = pk_bf16(EXP2F(e1[2]), EXP2F(e1[3]));
            const int dws = (8 * jt + 2 * g) ^ pat;
            *(uint2v*)(p0 + colbase + dws) = w0;
            *(uint2v*)(p1 + colbase + dws) = w1;
        }

        // B-fragments of P (same-wave LDS ordering; compiler inserts lgkmcnt waits)
        const int dlo = (4 * g) ^ pat, dhi = (16 + 4 * g) ^ pat;
        const bf16x8 bp00 = *(const bf16x8*)(p0 + colbase + dlo);
        const bf16x8 bp01 = *(const bf16x8*)(p0 + colbase + dhi);
        const bf16x8 bp10 = *(const bf16x8*)(p1 + colbase + dlo);
        const bf16x8 bp11 = *(const bf16x8*)(p1 + colbase + dhi);

        o00 = __builtin_amdgcn_mfma_f32_16x16x32_bf16(av0, bp00, o00, 0, 0, 0);
        o00 = __builtin_amdgcn_mfma_f32_16x16x32_bf16(av1, bp01, o00, 0, 0, 0);
        o01 = __builtin_amdgcn_mfma_f32_16x16x32_bf16(av2, bp00, o01, 0, 0, 0);
        o01 = __builtin_amdgcn_mfma_f32_16x16x32_bf16(av3, bp01, o01, 0, 0, 0);
        o10 = __builtin_amdgcn_mfma_f32_16x16x32_bf16(av0, bp10, o10, 0, 0, 0);
        o10 = __builtin_amdgcn_mfma_f32_16x16x32_bf16(av1, bp11, o10, 0, 0, 0);
        o11 = __builtin_amdgcn_mfma_f32_16x16x32_bf16(av2, bp10, o11, 0, 0, 0);
        o11 = __builtin_amdgcn_mfma_f32_16x16x32_bf16(av3, bp11, o11, 0, 0, 0);
    }

    const size_t bgb = (size_t)bg * HD * LSP;
#pragma unroll
    for (int r = 0; r < 4; ++r) {
        size_t i0 = bgb + (size_t)(4 * g + r) * LSP + kc0;
        out[i0] = o00[r] + x[i0];
        size_t i1 = bgb + (size_t)(16 + 4 * g + r) * LSP + kc0;
        out[i1] = o01[r] + x[i1];
        if (real1) {
            size_t i2 = bgb + (size_t)(4 * g + r) * LSP + kc1;
            out[i2] = o10[r] + x[i2];
            size_t i3 = bgb + (size_t)(16 + 4 * g + r) * LSP + kc1;
            out[i3] = o11[r] + x[i3];
        }
    }
}

extern "C" void kernel_launch(void* const* d_in, const int* in_sizes, int n_in,
                              void* d_out, int out_size, void* d_ws, size_t ws_size,
                              hipStream_t stream) {
    const float* x  = (const float*)d_in[0];
    const float* Wq = (const float*)d_in[1];
    const float* bq = (const float*)d_in[2];
    const float* Wk = (const float*)d_in[3];
    const float* bk = (const float*)d_in[4];
    const float* Wv = (const float*)d_in[5];
    const float* bv = (const float*)d_in[6];
    float* out = (float*)d_out;

    // workspace: qt | kt | v (all bf16) ~19.3 MB
    const size_t QSZ = (size_t)BG * HD * LSP;
    short* qt = (short*)d_ws;
    short* kt = qt + QSZ;
    short* v  = kt + QSZ;

    qkv_mfma<<<dim3(13, BG), TPB, 0, stream>>>(x, Wq, bq, Wk, bk, Wv, bv, qt, kt, v);
    z_mfma  <<<dim3(25, BG), TPB, 0, stream>>>(qt, kt, v);
    out_mfma<<<dim3(25, BG), TPB, 0, stream>>>(qt, kt, v, x, out);
}